// Round 3
// baseline (1070.915 us; speedup 1.0000x reference)
//
#include <hip/hip_runtime.h>
#include <hip/hip_bf16.h>
#include <cstdint>

// QuantizedLinear: Y[M,N] = X[M,K] . W^T + bias.  M=8192, N=16384, K=4096.
// Prepass: X f32->bf16, W (q-zp)*scale->bf16 into d_ws.
// GEMM: 256x256 tile, BK=64, 8 waves (2Mx4N), 128KiB LDS dbuf.
// Pipelined 4-phase schedule: ds_reads issued ONE PHASE AHEAD with counted
// lgkmcnt so the DS pipe overlaps the MFMA pipe (was lockstep-serial at 50%
// MfmaUtil). One barrier per phase. Counted vmcnt (2) once per K-tile.
// T2 xor-swizzle (0 bank conflicts), T5 setprio, XCD-swizzled grid,
// nontemporal C stores (keep A/B panels resident in L3).

#define M_DIM 8192
#define N_DIM 16384
#define K_DIM 4096
#define NT (K_DIM / 64)   // 64 k-tiles

using bf16x8 = __attribute__((ext_vector_type(8))) short;
using f32x4  = __attribute__((ext_vector_type(4))) float;

__device__ __forceinline__ unsigned short f2bf(float f) {
    union { float f; unsigned int u; } v; v.f = f;
    unsigned int lsb = (v.u >> 16) & 1u;
    v.u += 0x7fffu + lsb;
    return (unsigned short)(v.u >> 16);
}

__global__ void cvt_x_kernel(const float* __restrict__ x, unsigned short* __restrict__ o,
                             long long n) {
    long long i = (long long)blockIdx.x * blockDim.x + threadIdx.x;
    long long stride = (long long)gridDim.x * blockDim.x * 4;
    for (long long idx = i * 4; idx < n; idx += stride) {
        float4 v = *(const float4*)(x + idx);
        ushort4 r;
        r.x = f2bf(v.x); r.y = f2bf(v.y); r.z = f2bf(v.z); r.w = f2bf(v.w);
        *(ushort4*)(o + idx) = r;
    }
}

__global__ void cvt_w_kernel(const int* __restrict__ q, unsigned short* __restrict__ o,
                             const float* __restrict__ sp, const float* __restrict__ zp,
                             long long n) {
    float s = sp[0], z = zp[0];
    long long i = (long long)blockIdx.x * blockDim.x + threadIdx.x;
    long long stride = (long long)gridDim.x * blockDim.x * 4;
    for (long long idx = i * 4; idx < n; idx += stride) {
        int4 v = *(const int4*)(q + idx);
        ushort4 r;
        r.x = f2bf(((float)v.x - z) * s);
        r.y = f2bf(((float)v.y - z) * s);
        r.z = f2bf(((float)v.z - z) * s);
        r.w = f2bf(((float)v.w - z) * s);
        *(ushort4*)(o + idx) = r;
    }
}

#define SB() __builtin_amdgcn_sched_barrier(0)

__device__ __forceinline__ void barrier_() {
    SB();
    asm volatile("" ::: "memory");
    __builtin_amdgcn_s_barrier();
    asm volatile("" ::: "memory");
    SB();
}

// Stage one 128-row x 64-col half-tile (16 KiB) via 2x global_load_lds width-16.
// l0 = region base + wave*512 elems (wave-uniform); lanes write lane*16B.
// Global source is inverse-swizzled so that swizzled reads see linear data.
__device__ __forceinline__ void stage_half(const unsigned short* g0, unsigned short* l0) {
    __builtin_amdgcn_global_load_lds((const __attribute__((address_space(1))) void*)g0,
                                     (__attribute__((address_space(3))) void*)l0, 16, 0, 0);
    __builtin_amdgcn_global_load_lds(
        (const __attribute__((address_space(1))) void*)(g0 + (size_t)64 * K_DIM),
        (__attribute__((address_space(3))) void*)(l0 + 4096), 16, 0, 0);
}

__global__ __launch_bounds__(512, 2) void gemm256_kernel(const unsigned short* __restrict__ A,
                                                         const unsigned short* __restrict__ B,
                                                         const float* __restrict__ bias,
                                                         float* __restrict__ C) {
    extern __shared__ unsigned short smem[];   // 128 KiB: 2 bufs x (A 16K + B 16K elems)

    const int tid  = threadIdx.x;
    const int wave = tid >> 6;
    const int lane = tid & 63;
    const int fr = lane & 15, hi = lane >> 4;
    const int wr = wave >> 2, wc = wave & 3;

    // XCD-aware bijective swizzle: nwg = 32*64 = 2048, divisible by 8.
    const int nwg = (M_DIM / 256) * (N_DIM / 256);
    const int cpx = nwg >> 3;
    const int swz = (blockIdx.x & 7) * cpx + (blockIdx.x >> 3);
    const int ntn = N_DIM / 256;
    const int tileRow = (swz / ntn) * 256;
    const int tileCol = (swz % ntn) * 256;

    // ---- staging addressing ----
    const size_t goff = (size_t)(tid >> 3) * K_DIM + (((tid & 7) ^ ((tid >> 3) & 7)) * 8);
    const unsigned short* Au  = A + (size_t)tileRow * K_DIM + goff;
    const unsigned short* Bu  = B + (size_t)tileCol * K_DIM + goff;
    const unsigned short* AuH = Au + (size_t)128 * K_DIM;
    const unsigned short* BuH = Bu + (size_t)128 * K_DIM;

    // ---- read addressing (swizzled) ----
    const int c0 = (0 * 32 + hi * 8) ^ ((fr & 7) << 3);
    const int c1 = (1 * 32 + hi * 8) ^ ((fr & 7) << 3);
    const int aoff = wr * 8192 + fr * 64;
    const int boff = 16384 + (wc >> 1) * 8192 + ((wc & 1) * 64 + fr) * 64;

    f32x4 acc[8][4] = {};
    bf16x8 arA[4][2], arB[4][2], b0r[2][2], b1r[2][2];

    // ---- prologue: tile0 full (buf0) + tile1 Bh0,Ah0 (buf1) ----
    {
        unsigned short* lw0 = smem + wave * 512;
        unsigned short* lw1 = smem + 32768 + wave * 512;
        stage_half(Au,  lw0);            // t0 Ah0
        stage_half(AuH, lw0 + 8192);     // t0 Ah1
        stage_half(Bu,  lw0 + 16384);    // t0 Bh0
        stage_half(BuH, lw0 + 24576);    // t0 Bh1
        stage_half(Bu + 64, lw1 + 16384);// t1 Bh0
        stage_half(Au + 64, lw1);        // t1 Ah0
    }
    SB();
    asm volatile("s_waitcnt vmcnt(4)" ::: "memory");   // tile0 landed
    barrier_();
    // boundary reads for t=0 (A0 then B0), counted into P1's lgkmcnt(4)
    #pragma unroll
    for (int m = 0; m < 4; ++m) {
        arA[m][0] = *(const bf16x8*)(smem + aoff + m * 1024 + c0);
        arA[m][1] = *(const bf16x8*)(smem + aoff + m * 1024 + c1);
    }
    #pragma unroll
    for (int n = 0; n < 2; ++n) {
        b0r[n][0] = *(const bf16x8*)(smem + boff + n * 1024 + c0);
        b0r[n][1] = *(const bf16x8*)(smem + boff + n * 1024 + c1);
    }
    SB();

    for (int t = 0; t < NT; ++t) {
        const unsigned short* sbr = smem + (t & 1) * 32768;
        const unsigned short* nxr = smem + ((t + 1) & 1) * 32768;
        unsigned short* sbw = smem + (t & 1) * 32768 + wave * 512;
        unsigned short* nxw = smem + ((t + 1) & 1) * 32768 + wave * 512;
        const int kn1 = (t + 1) * 64, kn2 = (t + 2) * 64;

        // ===== P1: stage Ah1(t+1); issue B1 reads; lgkm(4)[A0,B0 ready]; Q00 =====
        if (t + 1 < NT) stage_half(AuH + kn1, nxw + 8192);
        #pragma unroll
        for (int n = 0; n < 2; ++n) {
            b1r[n][0] = *(const bf16x8*)(sbr + boff + (n + 2) * 1024 + c0);
            b1r[n][1] = *(const bf16x8*)(sbr + boff + (n + 2) * 1024 + c1);
        }
        SB();
        asm volatile("s_waitcnt lgkmcnt(4)" ::: "memory");
        SB();
        __builtin_amdgcn_s_setprio(1);
        #pragma unroll
        for (int m = 0; m < 4; ++m)
            #pragma unroll
            for (int n = 0; n < 2; ++n) {
                acc[m][n] = __builtin_amdgcn_mfma_f32_16x16x32_bf16(arA[m][0], b0r[n][0], acc[m][n], 0, 0, 0);
                acc[m][n] = __builtin_amdgcn_mfma_f32_16x16x32_bf16(arA[m][1], b0r[n][1], acc[m][n], 0, 0, 0);
            }
        __builtin_amdgcn_s_setprio(0);
        barrier_();

        // ===== P2: stage Bh1(t+1); issue A1 reads; lgkm(8)[B1 ready]; Q01 =====
        if (t + 1 < NT) stage_half(BuH + kn1, nxw + 24576);
        #pragma unroll
        for (int m = 0; m < 4; ++m) {
            arB[m][0] = *(const bf16x8*)(sbr + aoff + 4096 + m * 1024 + c0);
            arB[m][1] = *(const bf16x8*)(sbr + aoff + 4096 + m * 1024 + c1);
        }
        SB();
        asm volatile("s_waitcnt lgkmcnt(8)" ::: "memory");
        SB();
        __builtin_amdgcn_s_setprio(1);
        #pragma unroll
        for (int m = 0; m < 4; ++m)
            #pragma unroll
            for (int n = 0; n < 2; ++n) {
                acc[m][n + 2] = __builtin_amdgcn_mfma_f32_16x16x32_bf16(arA[m][0], b1r[n][0], acc[m][n + 2], 0, 0, 0);
                acc[m][n + 2] = __builtin_amdgcn_mfma_f32_16x16x32_bf16(arA[m][1], b1r[n][1], acc[m][n + 2], 0, 0, 0);
            }
        __builtin_amdgcn_s_setprio(0);
        barrier_();

        // ===== P3: stage Bh0(t+2); lgkm(0)[A1 ready]; Q11; counted vmcnt; barrier =====
        if (t + 2 < NT) stage_half(Bu + kn2, sbw + 16384);
        SB();
        asm volatile("s_waitcnt lgkmcnt(0)" ::: "memory");
        SB();
        __builtin_amdgcn_s_setprio(1);
        #pragma unroll
        for (int m = 0; m < 4; ++m)
            #pragma unroll
            for (int n = 0; n < 2; ++n) {
                acc[m + 4][n + 2] = __builtin_amdgcn_mfma_f32_16x16x32_bf16(arB[m][0], b1r[n][0], acc[m + 4][n + 2], 0, 0, 0);
                acc[m + 4][n + 2] = __builtin_amdgcn_mfma_f32_16x16x32_bf16(arB[m][1], b1r[n][1], acc[m + 4][n + 2], 0, 0, 0);
            }
        __builtin_amdgcn_s_setprio(0);
        SB();
        if (t + 2 < NT) {
            asm volatile("s_waitcnt vmcnt(2)" ::: "memory");   // tile t+1 fully landed
        } else {
            asm volatile("s_waitcnt vmcnt(0)" ::: "memory");   // tail drain
        }
        barrier_();

        // ===== P4: boundary A0(t+1) reads (overlap Q10); stage Ah0(t+2); Q10; B0(t+1) reads =====
        if (t + 1 < NT) {
            #pragma unroll
            for (int m = 0; m < 4; ++m) {
                arA[m][0] = *(const bf16x8*)(nxr + aoff + m * 1024 + c0);
                arA[m][1] = *(const bf16x8*)(nxr + aoff + m * 1024 + c1);
            }
        }
        if (t + 2 < NT) stage_half(Au + kn2, sbw);
        SB();
        __builtin_amdgcn_s_setprio(1);
        #pragma unroll
        for (int m = 0; m < 4; ++m)
            #pragma unroll
            for (int n = 0; n < 2; ++n) {
                acc[m + 4][n] = __builtin_amdgcn_mfma_f32_16x16x32_bf16(arB[m][0], b0r[n][0], acc[m + 4][n], 0, 0, 0);
                acc[m + 4][n] = __builtin_amdgcn_mfma_f32_16x16x32_bf16(arB[m][1], b0r[n][1], acc[m + 4][n], 0, 0, 0);
            }
        __builtin_amdgcn_s_setprio(0);
        if (t + 1 < NT) {   // WAR-safe: issued after Q10 consumed b0r
            #pragma unroll
            for (int n = 0; n < 2; ++n) {
                b0r[n][0] = *(const bf16x8*)(nxr + boff + n * 1024 + c0);
                b0r[n][1] = *(const bf16x8*)(nxr + boff + n * 1024 + c1);
            }
        }
        SB();
        barrier_();
    }

    // ---- epilogue: C/D layout col = lane&15, row = (lane>>4)*4 + j; nt stores ----
    #pragma unroll
    for (int m = 0; m < 8; ++m) {
        const int grow0 = tileRow + wr * 128 + m * 16 + hi * 4;
        #pragma unroll
        for (int n = 0; n < 4; ++n) {
            const int gcol = tileCol + wc * 64 + n * 16 + fr;
            const float bv = bias[gcol];
            #pragma unroll
            for (int j = 0; j < 4; ++j)
                __builtin_nontemporal_store(acc[m][n][j] + bv,
                                            &C[(size_t)(grow0 + j) * N_DIM + gcol]);
        }
    }
}

// Fallback (only if ws too small): basic LDS-tiled f32 GEMM.
__global__ void gemm_naive(const float* __restrict__ x, const int* __restrict__ wq,
                           const float* __restrict__ sp, const float* __restrict__ zp,
                           const float* __restrict__ bias, float* __restrict__ out) {
    __shared__ float sX[32][33];
    __shared__ float sW[32][33];
    const float s = sp[0], z = zp[0];
    const int tx = threadIdx.x & 15, ty = threadIdx.x >> 4;
    const int row0 = blockIdx.y * 32, col0 = blockIdx.x * 32;
    float acc[2][2] = {};
    for (int k0 = 0; k0 < K_DIM; k0 += 32) {
        for (int i = threadIdx.x; i < 32 * 32; i += 256) {
            int r = i >> 5, c = i & 31;
            sX[r][c] = x[(size_t)(row0 + r) * K_DIM + k0 + c];
            sW[r][c] = ((float)wq[(size_t)(col0 + r) * K_DIM + k0 + c] - z) * s;
        }
        __syncthreads();
        #pragma unroll
        for (int k = 0; k < 32; ++k) {
            float xa0 = sX[ty * 2][k], xa1 = sX[ty * 2 + 1][k];
            float wb0 = sW[tx * 2][k], wb1 = sW[tx * 2 + 1][k];
            acc[0][0] += xa0 * wb0; acc[0][1] += xa0 * wb1;
            acc[1][0] += xa1 * wb0; acc[1][1] += xa1 * wb1;
        }
        __syncthreads();
    }
    #pragma unroll
    for (int i = 0; i < 2; ++i)
        #pragma unroll
        for (int j = 0; j < 2; ++j)
            out[(size_t)(row0 + ty * 2 + i) * N_DIM + (col0 + tx * 2 + j)] =
                acc[i][j] + bias[col0 + tx * 2 + j];
}

extern "C" void kernel_launch(void* const* d_in, const int* in_sizes, int n_in,
                              void* d_out, int out_size, void* d_ws, size_t ws_size,
                              hipStream_t stream) {
    const float* x     = (const float*)d_in[0];
    const int*   wq    = (const int*)d_in[1];
    const float* scale = (const float*)d_in[2];
    const float* zp    = (const float*)d_in[3];
    const float* bias  = (const float*)d_in[4];
    float* out = (float*)d_out;

    const size_t needA = (size_t)M_DIM * K_DIM * sizeof(unsigned short);
    const size_t needB = (size_t)N_DIM * K_DIM * sizeof(unsigned short);

    if (ws_size >= needA + needB) {
        unsigned short* xb = (unsigned short*)d_ws;
        unsigned short* wb = xb + (size_t)M_DIM * K_DIM;
        cvt_x_kernel<<<2048, 256, 0, stream>>>(x, xb, (long long)M_DIM * K_DIM);
        cvt_w_kernel<<<2048, 256, 0, stream>>>(wq, wb, scale, zp, (long long)N_DIM * K_DIM);
        (void)hipFuncSetAttribute((const void*)gemm256_kernel,
                                  hipFuncAttributeMaxDynamicSharedMemorySize, 131072);
        gemm256_kernel<<<(M_DIM / 256) * (N_DIM / 256), 512, 131072, stream>>>(xb, wb, bias, out);
    } else {
        dim3 grid(N_DIM / 32, M_DIM / 32);
        gemm_naive<<<grid, 256, 0, stream>>>(x, wq, scale, zp, bias, out);
    }
}

// Round 4
// 684.935 us; speedup vs baseline: 1.5635x; 1.5635x over previous
//
#include <hip/hip_runtime.h>
#include <hip/hip_bf16.h>
#include <cstdint>

// QuantizedLinear: Y[M,N] = X[M,K] . W^T + bias.  M=8192, N=16384, K=4096.
// INT8 path: W (int8-valued) -> i8 exactly; X -> per-row absmax i8 (+ row-sum
// for exact zero-point correction).  GEMM with mfma_i32_32x32x32_i8:
// 256x256 tile, BK=128 (=128-byte rows), 8 waves (2Mx4N), 128 KiB LDS dbuf,
// pipelined 4-phase schedule (reads one phase ahead, counted lgkm/vmcnt),
// T2 xor-swizzle, T5 setprio, XCD-swizzled grid.
// Epilogue: y = s_w*(sx[row]*dot - zp*sx_rowsum[row]) + bias[col].

#define M_DIM 8192
#define N_DIM 16384
#define K_DIM 4096
#define BK    128
#define NT    (K_DIM / BK)   // 32 k-tiles

using i32x4  = __attribute__((ext_vector_type(4))) int;
using i32x16 = __attribute__((ext_vector_type(16))) int;

// ---------------- prepass: X -> i8 per-row absmax ----------------
__global__ __launch_bounds__(256) void quant_x_kernel(const float* __restrict__ x,
                                                      signed char* __restrict__ xq,
                                                      float* __restrict__ rs1,
                                                      float* __restrict__ rs2) {
    const int row = blockIdx.x;                 // 8192 rows
    const float* xr = x + (size_t)row * K_DIM;
    const int tid = threadIdx.x;

    float4 v[4];
    float amax = 0.f;
    #pragma unroll
    for (int j = 0; j < 4; ++j) {
        v[j] = *(const float4*)(xr + j * 1024 + tid * 4);
        amax = fmaxf(amax, fmaxf(fmaxf(fabsf(v[j].x), fabsf(v[j].y)),
                                 fmaxf(fabsf(v[j].z), fabsf(v[j].w))));
    }
    #pragma unroll
    for (int off = 32; off > 0; off >>= 1)
        amax = fmaxf(amax, __shfl_xor(amax, off));
    __shared__ float smax[4];
    __shared__ int   ssum[4];
    const int wv = tid >> 6, ln = tid & 63;
    if (ln == 0) smax[wv] = amax;
    __syncthreads();
    amax = fmaxf(fmaxf(smax[0], smax[1]), fmaxf(smax[2], smax[3]));
    const float s   = amax * (1.0f / 127.0f);
    const float inv = amax > 0.f ? 127.0f / amax : 0.f;

    int sum = 0;
    #pragma unroll
    for (int j = 0; j < 4; ++j) {
        int q0 = (int)__builtin_rintf(v[j].x * inv);
        int q1 = (int)__builtin_rintf(v[j].y * inv);
        int q2 = (int)__builtin_rintf(v[j].z * inv);
        int q3 = (int)__builtin_rintf(v[j].w * inv);
        sum += q0 + q1 + q2 + q3;
        int packed = (q0 & 255) | ((q1 & 255) << 8) | ((q2 & 255) << 16) | ((q3 & 255) << 24);
        *(int*)(xq + (size_t)row * K_DIM + j * 1024 + tid * 4) = packed;
    }
    #pragma unroll
    for (int off = 32; off > 0; off >>= 1)
        sum += __shfl_xor(sum, off);
    if (ln == 0) ssum[wv] = sum;
    __syncthreads();
    if (tid == 0) {
        int t = ssum[0] + ssum[1] + ssum[2] + ssum[3];
        rs1[row] = s;
        rs2[row] = s * (float)t;
    }
}

// ---------------- prepass: W int32 -> i8 (exact, values in [-128,127]) ----------------
__global__ void quant_w_kernel(const int* __restrict__ q, signed char* __restrict__ o,
                               long long n) {
    long long i = ((long long)blockIdx.x * blockDim.x + threadIdx.x) * 4;
    const long long stride = (long long)gridDim.x * blockDim.x * 4;
    for (; i < n; i += stride) {
        int4 v = *(const int4*)(q + i);
        int packed = (v.x & 255) | ((v.y & 255) << 8) | ((v.z & 255) << 16) | ((v.w & 255) << 24);
        *(int*)(o + i) = packed;
    }
}

// ---------------- GEMM ----------------
#define SB() __builtin_amdgcn_sched_barrier(0)

__device__ __forceinline__ void barrier_() {
    SB();
    asm volatile("" ::: "memory");
    __builtin_amdgcn_s_barrier();
    asm volatile("" ::: "memory");
    SB();
}

// Stage one 128-row x 128-byte half-tile (16 KiB) via 2x global_load_lds w16.
// l0 = region base + wave*1024 (wave-uniform); lanes write lane*16B.
// Global source inverse-swizzled: LDS[r][c16] = G[r][c16 ^ (r&7)].
__device__ __forceinline__ void stage_half8(const signed char* g0, unsigned char* l0) {
    __builtin_amdgcn_global_load_lds((const __attribute__((address_space(1))) void*)g0,
                                     (__attribute__((address_space(3))) void*)l0, 16, 0, 0);
    __builtin_amdgcn_global_load_lds(
        (const __attribute__((address_space(1))) void*)(g0 + (size_t)64 * K_DIM),
        (__attribute__((address_space(3))) void*)(l0 + 8192), 16, 0, 0);
}

__global__ __launch_bounds__(512, 2) void gemm_i8_kernel(const signed char* __restrict__ A,
                                                         const signed char* __restrict__ B,
                                                         const float* __restrict__ rs1,
                                                         const float* __restrict__ rs2,
                                                         const float* __restrict__ scale,
                                                         const float* __restrict__ zpp,
                                                         const float* __restrict__ bias,
                                                         float* __restrict__ C) {
    extern __shared__ unsigned char smem[];   // 128 KiB: 2 bufs x (A 32K + B 32K bytes)

    const int tid  = threadIdx.x;
    const int wave = tid >> 6;
    const int lane = tid & 63;
    const int fr = lane & 31, klo = lane >> 5;
    const int wr = wave >> 2, wc = wave & 3;

    // XCD-aware bijective swizzle: nwg = 2048, divisible by 8.
    const int nwg = (M_DIM / 256) * (N_DIM / 256);
    const int cpx = nwg >> 3;
    const int swz = (blockIdx.x & 7) * cpx + (blockIdx.x >> 3);
    const int ntn = N_DIM / 256;
    const int tileRow = (swz / ntn) * 256;
    const int tileCol = (swz % ntn) * 256;

    // ---- staging addressing (bytes) ----
    const size_t goff = (size_t)(tid >> 3) * K_DIM + (((tid & 7) ^ ((tid >> 3) & 7)) * 16);
    const signed char* Au  = A + (size_t)tileRow * K_DIM + goff;
    const signed char* Bu  = B + (size_t)tileCol * K_DIM + goff;
    const signed char* AuH = Au + (size_t)128 * K_DIM;
    const signed char* BuH = Bu + (size_t)128 * K_DIM;

    // ---- read addressing (swizzled), all byte offsets ----
    const int rA = wr * 128 + fr;            // A row within tile (m*32 added later, mod-8 safe)
    const int rB = wc * 64 + fr;             // B row within tile
    const int aoffB = rA * 128;              // A region at +0
    const int boffB = 32768 + rB * 128;      // B region
    int cA[4], cB[4];
    #pragma unroll
    for (int ks = 0; ks < 4; ++ks) {
        cA[ks] = ((ks * 2 + klo) ^ (rA & 7)) * 16;
        cB[ks] = ((ks * 2 + klo) ^ (rB & 7)) * 16;
    }

    i32x16 acc[4][2] = {};
    i32x4 arA[2][4], arB[2][4], b0r[4], b1r[4];

    // ---- prologue: tile0 full (buf0) + tile1 Bh0,Ah0 (buf1) ----
    {
        unsigned char* w0 = smem + wave * 1024;
        unsigned char* w1 = smem + 65536 + wave * 1024;
        stage_half8(Au,  w0);              // t0 Ah0
        stage_half8(AuH, w0 + 16384);      // t0 Ah1
        stage_half8(Bu,  w0 + 32768);      // t0 Bh0
        stage_half8(BuH, w0 + 49152);      // t0 Bh1
        stage_half8(Bu + BK, w1 + 32768);  // t1 Bh0
        stage_half8(Au + BK, w1);          // t1 Ah0
    }
    SB();
    asm volatile("s_waitcnt vmcnt(4)" ::: "memory");   // tile0 landed
    barrier_();
    // boundary reads for t=0: arA (8) then b0r (4)
    #pragma unroll
    for (int m = 0; m < 2; ++m)
        #pragma unroll
        for (int ks = 0; ks < 4; ++ks)
            arA[m][ks] = *(const i32x4*)(smem + aoffB + m * 4096 + cA[ks]);
    #pragma unroll
    for (int ks = 0; ks < 4; ++ks)
        b0r[ks] = *(const i32x4*)(smem + boffB + cB[ks]);
    SB();

    for (int t = 0; t < NT; ++t) {
        const unsigned char* sbr = smem + (t & 1) * 65536;
        const unsigned char* nxr = smem + ((t + 1) & 1) * 65536;
        unsigned char* sbw = smem + (t & 1) * 65536 + wave * 1024;
        unsigned char* nxw = smem + ((t + 1) & 1) * 65536 + wave * 1024;
        const int kn1 = (t + 1) * BK, kn2 = (t + 2) * BK;

        // ===== P1: stage Ah1(t+1); issue b1r; lgkm(4)[arA,b0r ready]; Q(m01,n0) =====
        if (t + 1 < NT) stage_half8(AuH + kn1, nxw + 16384);
        #pragma unroll
        for (int ks = 0; ks < 4; ++ks)
            b1r[ks] = *(const i32x4*)(sbr + boffB + 4096 + cB[ks]);
        SB();
        asm volatile("s_waitcnt lgkmcnt(4)" ::: "memory");
        SB();
        __builtin_amdgcn_s_setprio(1);
        #pragma unroll
        for (int m = 0; m < 2; ++m)
            #pragma unroll
            for (int ks = 0; ks < 4; ++ks)
                acc[m][0] = __builtin_amdgcn_mfma_i32_32x32x32_i8(arA[m][ks], b0r[ks], acc[m][0], 0, 0, 0);
        __builtin_amdgcn_s_setprio(0);
        barrier_();

        // ===== P2: stage Bh1(t+1); issue arB; lgkm(8)[b1r ready]; Q(m01,n1) =====
        if (t + 1 < NT) stage_half8(BuH + kn1, nxw + 49152);
        #pragma unroll
        for (int m = 0; m < 2; ++m)
            #pragma unroll
            for (int ks = 0; ks < 4; ++ks)
                arB[m][ks] = *(const i32x4*)(sbr + aoffB + (m + 2) * 4096 + cA[ks]);
        SB();
        asm volatile("s_waitcnt lgkmcnt(8)" ::: "memory");
        SB();
        __builtin_amdgcn_s_setprio(1);
        #pragma unroll
        for (int m = 0; m < 2; ++m)
            #pragma unroll
            for (int ks = 0; ks < 4; ++ks)
                acc[m][1] = __builtin_amdgcn_mfma_i32_32x32x32_i8(arA[m][ks], b1r[ks], acc[m][1], 0, 0, 0);
        __builtin_amdgcn_s_setprio(0);
        barrier_();

        // ===== P3: stage Bh0(t+2); lgkm(0)[arB ready]; Q(m23,n1); counted vmcnt =====
        if (t + 2 < NT) stage_half8(Bu + kn2, sbw + 32768);
        SB();
        asm volatile("s_waitcnt lgkmcnt(0)" ::: "memory");
        SB();
        __builtin_amdgcn_s_setprio(1);
        #pragma unroll
        for (int m = 0; m < 2; ++m)
            #pragma unroll
            for (int ks = 0; ks < 4; ++ks)
                acc[m + 2][1] = __builtin_amdgcn_mfma_i32_32x32x32_i8(arB[m][ks], b1r[ks], acc[m + 2][1], 0, 0, 0);
        __builtin_amdgcn_s_setprio(0);
        SB();
        if (t + 2 < NT) {
            asm volatile("s_waitcnt vmcnt(2)" ::: "memory");   // tile t+1 fully landed
        } else {
            asm volatile("s_waitcnt vmcnt(0)" ::: "memory");   // tail drain
        }
        barrier_();

        // ===== P4: read arA(t+1); stage Ah0(t+2); Q(m23,n0); read b0r(t+1) =====
        if (t + 1 < NT) {
            #pragma unroll
            for (int m = 0; m < 2; ++m)
                #pragma unroll
                for (int ks = 0; ks < 4; ++ks)
                    arA[m][ks] = *(const i32x4*)(nxr + aoffB + m * 4096 + cA[ks]);
        }
        if (t + 2 < NT) stage_half8(Au + kn2, sbw);
        SB();
        __builtin_amdgcn_s_setprio(1);
        #pragma unroll
        for (int m = 0; m < 2; ++m)
            #pragma unroll
            for (int ks = 0; ks < 4; ++ks)
                acc[m + 2][0] = __builtin_amdgcn_mfma_i32_32x32x32_i8(arB[m][ks], b0r[ks], acc[m + 2][0], 0, 0, 0);
        __builtin_amdgcn_s_setprio(0);
        if (t + 1 < NT) {   // WAR-safe: after Q(m23,n0) consumed b0r
            #pragma unroll
            for (int ks = 0; ks < 4; ++ks)
                b0r[ks] = *(const i32x4*)(nxr + boffB + cB[ks]);
        }
        SB();
        barrier_();
    }

    // ---- epilogue: 32x32 C/D layout col=lane&31, row=(r&3)+8*(r>>2)+4*(lane>>5) ----
    const float sw  = scale[0];
    const float zpv = zpp[0];
    const float bv0 = bias[tileCol + wc * 64 + fr];
    const float bv1 = bias[tileCol + wc * 64 + 32 + fr];
    #pragma unroll
    for (int m = 0; m < 4; ++m) {
        #pragma unroll
        for (int r = 0; r < 16; ++r) {
            const int grow = tileRow + wr * 128 + m * 32 + (r & 3) + 8 * (r >> 2) + 4 * klo;
            const float f1 = rs1[grow] * sw;
            const float f2 = zpv * rs2[grow] * sw;
            const int gc0 = tileCol + wc * 64 + fr;
            C[(size_t)grow * N_DIM + gc0]      = f1 * (float)acc[m][0][r] - f2 + bv0;
            C[(size_t)grow * N_DIM + gc0 + 32] = f1 * (float)acc[m][1][r] - f2 + bv1;
        }
    }
}

// Fallback (only if ws too small): basic LDS-tiled f32 GEMM.
__global__ void gemm_naive(const float* __restrict__ x, const int* __restrict__ wq,
                           const float* __restrict__ sp, const float* __restrict__ zp,
                           const float* __restrict__ bias, float* __restrict__ out) {
    __shared__ float sX[32][33];
    __shared__ float sW[32][33];
    const float s = sp[0], z = zp[0];
    const int tx = threadIdx.x & 15, ty = threadIdx.x >> 4;
    const int row0 = blockIdx.y * 32, col0 = blockIdx.x * 32;
    float acc[2][2] = {};
    for (int k0 = 0; k0 < K_DIM; k0 += 32) {
        for (int i = threadIdx.x; i < 32 * 32; i += 256) {
            int r = i >> 5, c = i & 31;
            sX[r][c] = x[(size_t)(row0 + r) * K_DIM + k0 + c];
            sW[r][c] = ((float)wq[(size_t)(col0 + r) * K_DIM + k0 + c] - z) * s;
        }
        __syncthreads();
        #pragma unroll
        for (int k = 0; k < 32; ++k) {
            float xa0 = sX[ty * 2][k], xa1 = sX[ty * 2 + 1][k];
            float wb0 = sW[tx * 2][k], wb1 = sW[tx * 2 + 1][k];
            acc[0][0] += xa0 * wb0; acc[0][1] += xa0 * wb1;
            acc[1][0] += xa1 * wb0; acc[1][1] += xa1 * wb1;
        }
        __syncthreads();
    }
    #pragma unroll
    for (int i = 0; i < 2; ++i)
        #pragma unroll
        for (int j = 0; j < 2; ++j)
            out[(size_t)(row0 + ty * 2 + i) * N_DIM + (col0 + tx * 2 + j)] =
                acc[i][j] + bias[col0 + tx * 2 + j];
}

extern "C" void kernel_launch(void* const* d_in, const int* in_sizes, int n_in,
                              void* d_out, int out_size, void* d_ws, size_t ws_size,
                              hipStream_t stream) {
    const float* x     = (const float*)d_in[0];
    const int*   wq    = (const int*)d_in[1];
    const float* scale = (const float*)d_in[2];
    const float* zp    = (const float*)d_in[3];
    const float* bias  = (const float*)d_in[4];
    float* out = (float*)d_out;

    // ws layout: xq (32Mi) | wq8 (64Mi) | rs1 (32K f32) | rs2 (32K f32)
    const size_t offXq = 0;
    const size_t offWq = (size_t)M_DIM * K_DIM;
    const size_t offR1 = offWq + (size_t)N_DIM * K_DIM;
    const size_t offR2 = offR1 + (size_t)M_DIM * sizeof(float);
    const size_t need  = offR2 + (size_t)M_DIM * sizeof(float);

    if (ws_size >= need) {
        signed char* xq  = (signed char*)d_ws + offXq;
        signed char* wq8 = (signed char*)d_ws + offWq;
        float* rs1 = (float*)((char*)d_ws + offR1);
        float* rs2 = (float*)((char*)d_ws + offR2);
        quant_x_kernel<<<M_DIM, 256, 0, stream>>>(x, xq, rs1, rs2);
        quant_w_kernel<<<4096, 256, 0, stream>>>(wq, wq8, (long long)N_DIM * K_DIM);
        (void)hipFuncSetAttribute((const void*)gemm_i8_kernel,
                                  hipFuncAttributeMaxDynamicSharedMemorySize, 131072);
        gemm_i8_kernel<<<(M_DIM / 256) * (N_DIM / 256), 512, 131072, stream>>>(
            xq, wq8, rs1, rs2, scale, zp, bias, out);
    } else {
        dim3 grid(N_DIM / 32, M_DIM / 32);
        gemm_naive<<<grid, 256, 0, stream>>>(x, wq, scale, zp, bias, out);
    }
}